// Round 20
// baseline (519.998 us; speedup 1.0000x reference)
//
#include <hip/hip_runtime.h>

#define D 128
#define CHUNK 512
#define NSLICE 8
#define SLW 16            // cols per slice

using short8 = __attribute__((ext_vector_type(8))) short;
using f32x4  = __attribute__((ext_vector_type(4))) float;
using f32x2  = __attribute__((ext_vector_type(2))) float;
using u32x2  = __attribute__((ext_vector_type(2))) unsigned;

__device__ __forceinline__ unsigned short f2bf(float f){
  unsigned u = __builtin_bit_cast(unsigned, f);
  u += 0x7fffu + ((u >> 16) & 1u);           // round-to-nearest-even
  return (unsigned short)(u >> 16);
}
__device__ __forceinline__ float bflo2f(unsigned v){
  return __builtin_bit_cast(float, v << 16);
}
__device__ __forceinline__ float bfhi2f(unsigned v){
  return __builtin_bit_cast(float, v & 0xffff0000u);
}
__device__ __forceinline__ float bfs2f(unsigned short v){
  return __builtin_bit_cast(float, ((unsigned)v) << 16);
}
// packed f32x2 -> 2xbf16 in one instruction (gfx950)
__device__ __forceinline__ unsigned cvtpk(float lo, float hi){
  unsigned r;
  asm("v_cvt_pk_bf16_f32 %0, %1, %2" : "=v"(r) : "v"(lo), "v"(hi));
  return r;
}

// padded segment length: ceil((d+1)/4)*4  (>= d+1, multiple of 4, >=1 pad)
__device__ __forceinline__ int plen4(int d){ return (d + 4) & ~3; }

// ---------------- degree + per-edge rank (atomic return value) ------------
__global__ void k_deg(const int* __restrict__ dst, int* __restrict__ deg,
                      int* __restrict__ rank, int E){
  int e = blockIdx.x * 256 + threadIdx.x;
  if (e < E) rank[e] = atomicAdd(&deg[dst[e]], 1);
}

// ---------------- scan over PADDED degrees (3-stage) ----------------
__global__ void k_chunksum(const int* __restrict__ deg, int* __restrict__ csum, int n){
  __shared__ int s[256];
  int tid = threadIdx.x;
  int n0 = blockIdx.x * CHUNK + tid * 2;
  int v = 0;
  if (n0     < n) v += plen4(deg[n0]);
  if (n0 + 1 < n) v += plen4(deg[n0 + 1]);
  s[tid] = v; __syncthreads();
  for (int off = 128; off > 0; off >>= 1){
    if (tid < off) s[tid] += s[tid + off];
    __syncthreads();
  }
  if (tid == 0) csum[blockIdx.x] = s[0];
}

__global__ void k_scanchunks(int* __restrict__ csum, int nchunks){
  __shared__ int s[256];
  int tid = threadIdx.x;
  int v = (tid < nchunks) ? csum[tid] : 0;
  s[tid] = v; __syncthreads();
  for (int off = 1; off < 256; off <<= 1){
    int t = (tid >= off) ? s[tid - off] : 0;
    __syncthreads();
    s[tid] += t;
    __syncthreads();
  }
  if (tid < nchunks) csum[tid] = s[tid] - v;   // exclusive
}

__global__ void k_offsets(const int* __restrict__ deg, const int* __restrict__ csum,
                          int* __restrict__ offs, float* __restrict__ inv, int n){
  __shared__ int s[256];
  int tid = threadIdx.x;
  int n0 = blockIdx.x * CHUNK + tid * 2;
  int d0 = (n0     < n) ? deg[n0]     : 0;
  int d1 = (n0 + 1 < n) ? deg[n0 + 1] : 0;
  int p0 = (n0     < n) ? plen4(d0) : 0;
  int p1 = (n0 + 1 < n) ? plen4(d1) : 0;
  int pair = p0 + p1;
  s[tid] = pair; __syncthreads();
  for (int off = 1; off < 256; off <<= 1){
    int t = (tid >= off) ? s[tid - off] : 0;
    __syncthreads();
    s[tid] += t;
    __syncthreads();
  }
  int excl = s[tid] - pair + csum[blockIdx.x];
  if (n0     <= n) offs[n0]     = excl;
  if (n0 + 1 <= n) offs[n0 + 1] = excl + p0;
  if (n0     < n) inv[n0]     = rsqrtf((float)(d0 + 1));
  if (n0 + 1 < n) inv[n0 + 1] = rsqrtf((float)(d1 + 1));
}

// ---------------- fill padding entries with sentinel (zero row index n) ----
__global__ void k_fillpad(const int* __restrict__ deg, const int* __restrict__ offs,
                          int* __restrict__ csrc, int n){
  int i = blockIdx.x * 256 + threadIdx.x;
  if (i >= n) return;
  int s = offs[i] + deg[i];
  int e = offs[i + 1];
  for (int j = s; j < e; ++j) csrc[j] = n;
}

// ---------------- zero the sentinel row of each hw slice -------------------
__global__ void k_zrow(unsigned short* __restrict__ hwS, int n){
  int tid = threadIdx.x;               // 128 = 8 slices x 16 cols
  int sl = tid >> 4, c = tid & 15;
  hwS[((long)sl * (n + 1) + n) * 16 + c] = 0;
}

// ---------------- CSR fill (XCD-partitioned, atomic-free via rank) ---------
__global__ __launch_bounds__(256)
void k_csrfill(const int* __restrict__ src, const int* __restrict__ dst,
               const int* __restrict__ offs, const int* __restrict__ rank,
               int* __restrict__ csrc, int E, int n){
  int part = blockIdx.x & 7;
  int blk  = blockIdx.x >> 3;
  int nblk = gridDim.x >> 3;
  int per = (n + 7) / 8;
  int d0 = part * per, d1 = min(d0 + per, n);
  int stride = nblk * 256;
  for (int e = blk * 256 + threadIdx.x; e < E; e += stride){
    int d = dst[e];
    if (d >= d0 && d < d1){
      csrc[offs[d] + rank[e]] = src[e];
    }
  }
}

// ---------------- GEMM (fused BN of previous layer): hwS = act(h) @ W ------
// hwS has n+1 rows per slice (row n = zero sentinel); agg input has n rows.
#define WSTRIDE 136
__global__ __launch_bounds__(512)
void k_gemm(const float* __restrict__ hf, const unsigned short* __restrict__ hb,
            const float* __restrict__ W, const float* __restrict__ inv,
            const float* __restrict__ stats, const float* __restrict__ gamma,
            const float* __restrict__ beta, float invn,
            int do_norm, unsigned short* __restrict__ hwS, int nrows){
  __shared__ unsigned short Wt[128 * WSTRIDE];  // transposed, padded
  __shared__ float s_sc[128], s_sh[128];
  int tid = threadIdx.x;
  if (do_norm && tid < 128){
    float mean = stats[tid] * invn;
    float var = stats[128 + tid] * invn - mean * mean;
    float isd = rsqrtf(var + 1e-5f);
    float sc = gamma[tid] * isd;
    s_sc[tid] = sc;
    s_sh[tid] = beta[tid] - mean * sc;
  }
  for (int i = tid; i < 128 * 128; i += 512){
    int k = i >> 7, c = i & 127;
    Wt[c * WSTRIDE + k] = f2bf(W[i]);
  }
  __syncthreads();

  int wave = tid >> 6, lane = tid & 63;
  int r0 = blockIdx.x * 128 + wave * 16;
  int row = r0 + (lane & 15);
  int kg = lane >> 4;
  int rowc = row < nrows ? row : nrows - 1;

  short8 a[4];
  if (do_norm){
#pragma unroll
    for (int kt = 0; kt < 4; ++kt){
      int k0 = kt * 32 + kg * 8;                 // 8 cols within one slice
      int sl = k0 >> 4, o = k0 & 15;
      short8 raw = *(const short8*)(hb + ((long)sl * nrows + rowc) * SLW + o);
      unsigned u[4];
#pragma unroll
      for (int j = 0; j < 4; ++j){
        float lo = bfs2f((unsigned short)raw[2*j]);
        float hi = bfs2f((unsigned short)raw[2*j+1]);
        lo = fmaxf(0.f, lo * s_sc[k0+2*j]   + s_sh[k0+2*j]);
        hi = fmaxf(0.f, hi * s_sc[k0+2*j+1] + s_sh[k0+2*j+1]);
        u[j] = cvtpk(lo, hi);
      }
      a[kt] = *(short8*)u;
    }
  } else {
    const float* hrow = hf + (long)rowc * D;
#pragma unroll
    for (int kt = 0; kt < 4; ++kt){
      int k0 = kt * 32 + kg * 8;
      f32x4 v0 = *(const f32x4*)(hrow + k0);
      f32x4 v1 = *(const f32x4*)(hrow + k0 + 4);
      unsigned u[4];
      u[0] = cvtpk(v0[0], v0[1]);
      u[1] = cvtpk(v0[2], v0[3]);
      u[2] = cvtpk(v1[0], v1[1]);
      u[3] = cvtpk(v1[2], v1[3]);
      a[kt] = *(short8*)u;
    }
  }

  f32x4 acc[8] = {};
#pragma unroll
  for (int ct = 0; ct < 8; ++ct){
    int col = ct * 16 + (lane & 15);
    const unsigned short* bp = &Wt[col * WSTRIDE + kg * 8];
#pragma unroll
    for (int kt = 0; kt < 4; ++kt){
      short8 b = *(const short8*)(bp + kt * 32);
      acc[ct] = __builtin_amdgcn_mfma_f32_16x16x32_bf16(a[kt], b, acc[ct], 0, 0, 0);
    }
  }

  int colbase = lane & 15;
  int rowo = r0 + kg * 4;
  float ivr[4];
#pragma unroll
  for (int r = 0; r < 4; ++r) ivr[r] = inv[min(rowo + r, nrows - 1)];
#pragma unroll
  for (int ct = 0; ct < 8; ++ct){        // slice = ct (cols ct*16..ct*16+15)
#pragma unroll
    for (int r = 0; r < 4; ++r){
      int rr = rowo + r;
      if (rr < nrows)
        hwS[((long)ct * (nrows + 1) + rr) * SLW + colbase] = f2bf(acc[ct][r] * ivr[r]);
    }
  }
}

// ---------------- aggregate + BN partial stats (sliced, 16-node cohorts) ---
// Zero-row padded CSR: segments are multiples of 4 with >=1 sentinel entry
// (index n -> all-zero hw row). Inner loop gathers UNCONDITIONALLY — pad
// entries add 0. No cmp/cndmask predication; finished slots re-gather the
// zero row via min-clamp (L2-hot broadcast).
__global__ __launch_bounds__(256)
void k_agg(const unsigned short* __restrict__ hwS, const float* __restrict__ inv,
           const int* __restrict__ offs, const int* __restrict__ csrc,
           const float* __restrict__ bias,
           unsigned* __restrict__ aggS, float* __restrict__ stats, int n,
           int ngroups){
  int g   = blockIdx.x & 7;
  int grp = blockIdx.x >> 3;
  int tid = threadIdx.x, lane = tid & 63, wv = tid >> 6;
  int ns = lane >> 2;          // node slot 0..15
  int cp = lane & 3;           // col quad 0..3 (cols g*16 + cp*4 .. +3)
  int nwaves = ngroups * 4;
  int gw = grp * 4 + wv;
  int per = (n + nwaves - 1) / nwaves;
  per = (per + 15) & ~15;      // cohort-aligned chunks
  int n0 = min(gw * per, n), n1 = min(n0 + per, n);

  const u32x2* slice2 = (const u32x2*)((const unsigned*)hwS + (long)g * (n + 1) * 8);
  u32x2* oslice2 = (u32x2*)(aggS + (long)g * n * 8);

  int cb = g * 16 + cp * 4;
  float b0 = bias[cb], b1 = bias[cb + 1], b2 = bias[cb + 2], b3 = bias[cb + 3];
  float s0 = 0, s1 = 0, s2 = 0, s3 = 0;
  float q0 = 0, q1 = 0, q2 = 0, q3 = 0;

  for (int base = n0; base < n1; base += 16){
    int node = base + ns;
    bool act = node < n1;
    int ndc = act ? node : n1 - 1;
    int e  = offs[ndc];
    int ee = offs[ndc + 1];
    int em = ee - 1;             // last entry is always a sentinel (zero row)
    float a0 = 0, a1 = 0, a2 = 0, a3 = 0;

    int i0 = csrc[e];
    int i1 = csrc[e + 1];
    int i2 = csrc[e + 2];
    int i3 = csrc[e + 3];
    while (__any(e < ee)){
      int j0 = csrc[min(e + 4, em)];
      int j1 = csrc[min(e + 5, em)];
      int j2 = csrc[min(e + 6, em)];
      int j3 = csrc[min(e + 7, em)];
      u32x2 v0 = slice2[(long)i0 * 4 + cp];
      u32x2 v1 = slice2[(long)i1 * 4 + cp];
      u32x2 v2 = slice2[(long)i2 * 4 + cp];
      u32x2 v3 = slice2[(long)i3 * 4 + cp];
      a0 += (bflo2f(v0[0]) + bflo2f(v1[0])) + (bflo2f(v2[0]) + bflo2f(v3[0]));
      a1 += (bfhi2f(v0[0]) + bfhi2f(v1[0])) + (bfhi2f(v2[0]) + bfhi2f(v3[0]));
      a2 += (bflo2f(v0[1]) + bflo2f(v1[1])) + (bflo2f(v2[1]) + bflo2f(v3[1]));
      a3 += (bfhi2f(v0[1]) + bfhi2f(v1[1])) + (bfhi2f(v2[1]) + bfhi2f(v3[1]));
      i0 = j0; i1 = j1; i2 = j2; i3 = j3;
      e += 4;
    }

    if (act){
      u32x2 sv = slice2[(long)node * 4 + cp];
      float ivd = inv[node];
      a0 = (a0 + bflo2f(sv[0])) * ivd + b0;
      a1 = (a1 + bfhi2f(sv[0])) * ivd + b1;
      a2 = (a2 + bflo2f(sv[1])) * ivd + b2;
      a3 = (a3 + bfhi2f(sv[1])) * ivd + b3;
      u32x2 pk;
      pk[0] = ((unsigned)f2bf(a1) << 16) | (unsigned)f2bf(a0);
      pk[1] = ((unsigned)f2bf(a3) << 16) | (unsigned)f2bf(a2);
      __builtin_nontemporal_store(pk, oslice2 + (long)node * 4 + cp);
      s0 += a0; s1 += a1; s2 += a2; s3 += a3;
      q0 += a0 * a0; q1 += a1 * a1; q2 += a2 * a2; q3 += a3 * a3;
    }
  }

  // fold the 16 node slots (lane bits 2..5) once per kernel
#pragma unroll
  for (int off = 4; off <= 32; off <<= 1){
    s0 += __shfl_xor(s0, off, 64); s1 += __shfl_xor(s1, off, 64);
    s2 += __shfl_xor(s2, off, 64); s3 += __shfl_xor(s3, off, 64);
    q0 += __shfl_xor(q0, off, 64); q1 += __shfl_xor(q1, off, 64);
    q2 += __shfl_xor(q2, off, 64); q3 += __shfl_xor(q3, off, 64);
  }

  __shared__ float red[4][4][8];
  if (ns == 0){
    red[wv][cp][0] = s0; red[wv][cp][1] = s1;
    red[wv][cp][2] = s2; red[wv][cp][3] = s3;
    red[wv][cp][4] = q0; red[wv][cp][5] = q1;
    red[wv][cp][6] = q2; red[wv][cp][7] = q3;
  }
  __syncthreads();
  if (tid < 4){
    float t[8] = {0,0,0,0,0,0,0,0};
#pragma unroll
    for (int w = 0; w < 4; ++w)
#pragma unroll
      for (int j = 0; j < 8; ++j) t[j] += red[w][tid][j];
    int c = g * 16 + tid * 4;
#pragma unroll
    for (int j = 0; j < 4; ++j){
      atomicAdd(&stats[c + j],       t[j]);
      atomicAdd(&stats[128 + c + j], t[4 + j]);
    }
  }
}

// ---------------- pool (fused BN+ReLU of layer 2, sliced bf16 agg) ---------
__global__ __launch_bounds__(256)
void k_pool(const unsigned* __restrict__ aggS, const float* __restrict__ stats,
            const float* __restrict__ gamma, const float* __restrict__ beta,
            float invn, const int* __restrict__ batch,
            float* __restrict__ out, int n){
  __shared__ float psc[128], psh[128];
  int tid = threadIdx.x, lane = tid & 63, wv = tid >> 6;
  if (tid < 128){
    float mean = stats[tid] * invn;
    float var = stats[128 + tid] * invn - mean * mean;
    float isd = rsqrtf(var + 1e-5f);
    float sc = gamma[tid] * isd;
    psc[tid] = sc;
    psh[tid] = beta[tid] - mean * sc;
  }
  __syncthreads();
  int gw = blockIdx.x * 4 + wv;
  int n0 = gw * 64;
  if (n0 >= n) return;
  int n1 = min(n0 + 64, n);
  int c0 = lane * 2;
  int sl = lane >> 3, cp = lane & 7;
  long sbase = (long)sl * n * 8;
  float sc0 = psc[c0], sc1 = psc[c0 + 1];
  float sh0 = psh[c0], sh1 = psh[c0 + 1];
  int g = batch[n0];
  float a0 = 0, a1 = 0;
  for (int nd = n0; nd < n1; ++nd){
    int gn = batch[nd];
    if (gn != g){
      atomicAdd(&out[(long)g * D + c0],     a0);
      atomicAdd(&out[(long)g * D + c0 + 1], a1);
      a0 = 0; a1 = 0; g = gn;
    }
    unsigned v = aggS[sbase + (long)nd * 8 + cp];
    a0 += fmaxf(0.f, bflo2f(v) * sc0 + sh0);
    a1 += fmaxf(0.f, bfhi2f(v) * sc1 + sh1);
  }
  atomicAdd(&out[(long)g * D + c0],     a0);
  atomicAdd(&out[(long)g * D + c0 + 1], a1);
}

extern "C" void kernel_launch(void* const* d_in, const int* in_sizes, int n_in,
                              void* d_out, int out_size, void* d_ws, size_t ws_size,
                              hipStream_t stream){
  const float* x      = (const float*)d_in[0];
  const int*   ei     = (const int*)d_in[1];
  const int*   batch  = (const int*)d_in[2];
  const float* Ws     = (const float*)d_in[3];
  const float* bs     = (const float*)d_in[4];
  const float* gammas = (const float*)d_in[5];
  const float* betas  = (const float*)d_in[6];

  const int E_ = in_sizes[1] / 2;
  const int N_ = in_sizes[2];
  const int* src = ei;
  const int* dst = ei + E_;

  char* p = (char*)d_ws;
  auto alloc = [&](size_t bytes) -> void* {
    void* r = (void*)p;
    p += (bytes + 255) & ~(size_t)255;
    return r;
  };
  unsigned*       bufA   = (unsigned*)      alloc((size_t)N_ * D * 2);          // bf16 agg, sliced
  unsigned short* hwS    = (unsigned short*)alloc((size_t)(N_ + 1) * D * 2);    // bf16 hw + zero row
  int*            deg    = (int*)           alloc((size_t)N_ * 4);
  float*          inv    = (float*)         alloc((size_t)N_ * 4);
  int*            offs   = (int*)           alloc((size_t)(N_ + 1) * 4);
  int*            rank   = (int*)           alloc((size_t)E_ * 4);
  int*            csrc   = (int*)           alloc(((size_t)E_ + 4 * N_ + 64) * 4); // padded
  float*          stats  = (float*)         alloc(3 * 256 * 4);
  int*            csum   = (int*)           alloc(256 * 4);

  hipMemsetAsync(deg,    0, (size_t)N_ * 4, stream);
  hipMemsetAsync(stats,  0, 3 * 256 * 4, stream);
  hipMemsetAsync(d_out,  0, (size_t)out_size * 4, stream);

  float invn = 1.0f / (float)N_;
  int nchunks = (N_ + CHUNK - 1) / CHUNK;
  k_deg       <<<(E_ + 255) / 256, 256, 0, stream>>>(dst, deg, rank, E_);
  k_chunksum  <<<nchunks, 256, 0, stream>>>(deg, csum, N_);
  k_scanchunks<<<1, 256, 0, stream>>>(csum, nchunks);
  k_offsets   <<<nchunks, 256, 0, stream>>>(deg, csum, offs, inv, N_);
  k_fillpad   <<<(N_ + 255) / 256, 256, 0, stream>>>(deg, offs, csrc, N_);
  k_csrfill   <<<2048, 256, 0, stream>>>(src, dst, offs, rank, csrc, E_, N_);
  k_zrow      <<<1, 128, 0, stream>>>(hwS, N_);

  int gemm_blocks = (N_ + 127) / 128;
  int ngroups = 256;
  for (int l = 0; l < 3; ++l){
    const float* st = (l == 0) ? stats : stats + (size_t)(l - 1) * 256;
    const float* gm = (l == 0) ? gammas : gammas + (size_t)(l - 1) * D;
    const float* bt = (l == 0) ? betas : betas + (size_t)(l - 1) * D;
    k_gemm<<<gemm_blocks, 512, 0, stream>>>(x, (const unsigned short*)bufA,
                                            Ws + (size_t)l * D * D, inv,
                                            st, gm, bt, invn,
                                            (l == 0) ? 0 : 1, hwS, N_);
    k_agg<<<ngroups * 8, 256, 0, stream>>>(hwS, inv, offs, csrc, bs + (size_t)l * D,
                                           bufA, stats + (size_t)l * 256, N_, ngroups);
  }
  k_pool<<<(N_ + 255) / 256, 256, 0, stream>>>(bufA, stats + 2 * 256,
                                               gammas + 2 * D, betas + 2 * D, invn,
                                               batch, (float*)d_out, N_);
}

// Round 21
// 489.390 us; speedup vs baseline: 1.0625x; 1.0625x over previous
//
#include <hip/hip_runtime.h>

#define D 128
#define CHUNK 512
#define NSLICE 8
#define SLW 16            // cols per slice

using short8 = __attribute__((ext_vector_type(8))) short;
using f32x4  = __attribute__((ext_vector_type(4))) float;
using f32x2  = __attribute__((ext_vector_type(2))) float;
using u32x2  = __attribute__((ext_vector_type(2))) unsigned;

__device__ __forceinline__ unsigned short f2bf(float f){
  unsigned u = __builtin_bit_cast(unsigned, f);
  u += 0x7fffu + ((u >> 16) & 1u);           // round-to-nearest-even
  return (unsigned short)(u >> 16);
}
__device__ __forceinline__ float bflo2f(unsigned v){
  return __builtin_bit_cast(float, v << 16);
}
__device__ __forceinline__ float bfhi2f(unsigned v){
  return __builtin_bit_cast(float, v & 0xffff0000u);
}
__device__ __forceinline__ float bfs2f(unsigned short v){
  return __builtin_bit_cast(float, ((unsigned)v) << 16);
}
// packed f32x2 -> 2xbf16 in one instruction (gfx950)
__device__ __forceinline__ unsigned cvtpk(float lo, float hi){
  unsigned r;
  asm("v_cvt_pk_bf16_f32 %0, %1, %2" : "=v"(r) : "v"(lo), "v"(hi));
  return r;
}

// ---------------- degree + per-edge rank (atomic return value) ------------
__global__ void k_deg(const int* __restrict__ dst, int* __restrict__ deg,
                      int* __restrict__ rank, int E){
  int e = blockIdx.x * 256 + threadIdx.x;
  if (e < E) rank[e] = atomicAdd(&deg[dst[e]], 1);
}

// ---------------- scan (3-stage) ----------------
__global__ void k_chunksum(const int* __restrict__ deg, int* __restrict__ csum, int n){
  __shared__ int s[256];
  int tid = threadIdx.x;
  int n0 = blockIdx.x * CHUNK + tid * 2;
  int v = 0;
  if (n0     < n) v += deg[n0];
  if (n0 + 1 < n) v += deg[n0 + 1];
  s[tid] = v; __syncthreads();
  for (int off = 128; off > 0; off >>= 1){
    if (tid < off) s[tid] += s[tid + off];
    __syncthreads();
  }
  if (tid == 0) csum[blockIdx.x] = s[0];
}

__global__ void k_scanchunks(int* __restrict__ csum, int nchunks){
  __shared__ int s[256];
  int tid = threadIdx.x;
  int v = (tid < nchunks) ? csum[tid] : 0;
  s[tid] = v; __syncthreads();
  for (int off = 1; off < 256; off <<= 1){
    int t = (tid >= off) ? s[tid - off] : 0;
    __syncthreads();
    s[tid] += t;
    __syncthreads();
  }
  if (tid < nchunks) csum[tid] = s[tid] - v;   // exclusive
}

__global__ void k_offsets(const int* __restrict__ deg, const int* __restrict__ csum,
                          int* __restrict__ offs, float* __restrict__ inv, int n){
  __shared__ int s[256];
  int tid = threadIdx.x;
  int n0 = blockIdx.x * CHUNK + tid * 2;
  int d0 = (n0     < n) ? deg[n0]     : 0;
  int d1 = (n0 + 1 < n) ? deg[n0 + 1] : 0;
  int pair = d0 + d1;
  s[tid] = pair; __syncthreads();
  for (int off = 1; off < 256; off <<= 1){
    int t = (tid >= off) ? s[tid - off] : 0;
    __syncthreads();
    s[tid] += t;
    __syncthreads();
  }
  int excl = s[tid] - pair + csum[blockIdx.x];
  if (n0     <= n) offs[n0]     = excl;
  if (n0 + 1 <= n) offs[n0 + 1] = excl + d0;
  if (n0     < n) inv[n0]     = rsqrtf((float)(d0 + 1));
  if (n0 + 1 < n) inv[n0 + 1] = rsqrtf((float)(d1 + 1));
}

// ---------------- CSR fill (XCD-partitioned, atomic-free via rank) ---------
__global__ __launch_bounds__(256)
void k_csrfill(const int* __restrict__ src, const int* __restrict__ dst,
               const int* __restrict__ offs, const int* __restrict__ rank,
               int* __restrict__ csrc, int E, int n){
  int part = blockIdx.x & 7;
  int blk  = blockIdx.x >> 3;
  int nblk = gridDim.x >> 3;
  int per = (n + 7) / 8;
  int d0 = part * per, d1 = min(d0 + per, n);
  int stride = nblk * 256;
  for (int e = blk * 256 + threadIdx.x; e < E; e += stride){
    int d = dst[e];
    if (d >= d0 && d < d1){
      csrc[offs[d] + rank[e]] = src[e];
    }
  }
}

// ---------------- GEMM (fused BN of previous layer): hwS = act(h) @ W ------
#define WSTRIDE 136
__global__ __launch_bounds__(512)
void k_gemm(const float* __restrict__ hf, const unsigned short* __restrict__ hb,
            const float* __restrict__ W, const float* __restrict__ inv,
            const float* __restrict__ stats, const float* __restrict__ gamma,
            const float* __restrict__ beta, float invn,
            int do_norm, unsigned short* __restrict__ hwS, int nrows){
  __shared__ unsigned short Wt[128 * WSTRIDE];  // transposed, padded
  __shared__ float s_sc[128], s_sh[128];
  int tid = threadIdx.x;
  if (do_norm && tid < 128){
    float mean = stats[tid] * invn;
    float var = stats[128 + tid] * invn - mean * mean;
    float isd = rsqrtf(var + 1e-5f);
    float sc = gamma[tid] * isd;
    s_sc[tid] = sc;
    s_sh[tid] = beta[tid] - mean * sc;
  }
  for (int i = tid; i < 128 * 128; i += 512){
    int k = i >> 7, c = i & 127;
    Wt[c * WSTRIDE + k] = f2bf(W[i]);
  }
  __syncthreads();

  int wave = tid >> 6, lane = tid & 63;
  int r0 = blockIdx.x * 128 + wave * 16;
  int row = r0 + (lane & 15);
  int kg = lane >> 4;
  int rowc = row < nrows ? row : nrows - 1;

  short8 a[4];
  if (do_norm){
#pragma unroll
    for (int kt = 0; kt < 4; ++kt){
      int k0 = kt * 32 + kg * 8;                 // 8 cols within one slice
      int sl = k0 >> 4, o = k0 & 15;
      short8 raw = *(const short8*)(hb + ((long)sl * nrows + rowc) * SLW + o);
      unsigned u[4];
#pragma unroll
      for (int j = 0; j < 4; ++j){
        float lo = bfs2f((unsigned short)raw[2*j]);
        float hi = bfs2f((unsigned short)raw[2*j+1]);
        lo = fmaxf(0.f, lo * s_sc[k0+2*j]   + s_sh[k0+2*j]);
        hi = fmaxf(0.f, hi * s_sc[k0+2*j+1] + s_sh[k0+2*j+1]);
        u[j] = cvtpk(lo, hi);
      }
      a[kt] = *(short8*)u;
    }
  } else {
    const float* hrow = hf + (long)rowc * D;
#pragma unroll
    for (int kt = 0; kt < 4; ++kt){
      int k0 = kt * 32 + kg * 8;
      f32x4 v0 = *(const f32x4*)(hrow + k0);
      f32x4 v1 = *(const f32x4*)(hrow + k0 + 4);
      unsigned u[4];
      u[0] = cvtpk(v0[0], v0[1]);
      u[1] = cvtpk(v0[2], v0[3]);
      u[2] = cvtpk(v1[0], v1[1]);
      u[3] = cvtpk(v1[2], v1[3]);
      a[kt] = *(short8*)u;
    }
  }

  f32x4 acc[8] = {};
#pragma unroll
  for (int ct = 0; ct < 8; ++ct){
    int col = ct * 16 + (lane & 15);
    const unsigned short* bp = &Wt[col * WSTRIDE + kg * 8];
#pragma unroll
    for (int kt = 0; kt < 4; ++kt){
      short8 b = *(const short8*)(bp + kt * 32);
      acc[ct] = __builtin_amdgcn_mfma_f32_16x16x32_bf16(a[kt], b, acc[ct], 0, 0, 0);
    }
  }

  int colbase = lane & 15;
  int rowo = r0 + kg * 4;
  float ivr[4];
#pragma unroll
  for (int r = 0; r < 4; ++r) ivr[r] = inv[min(rowo + r, nrows - 1)];
#pragma unroll
  for (int ct = 0; ct < 8; ++ct){        // slice = ct (cols ct*16..ct*16+15)
#pragma unroll
    for (int r = 0; r < 4; ++r){
      int rr = rowo + r;
      if (rr < nrows)
        hwS[((long)ct * nrows + rr) * SLW + colbase] = f2bf(acc[ct][r] * ivr[r]);
    }
  }
}

// ---------------- aggregate + BN partial stats (sliced, 16-node cohorts) ---
// slice g = blockIdx%8 -> one XCD, contiguous node chunk per wave.
// lane = node-slot(ns,16) x col-quad(cp,4); uint2 gathers (8B = 4 cols);
// 4 edges/iter with cross-iteration index prefetch; 512B NT flush.
// Per-wave chunk rounded to multiple of 16 -> all cohorts full.
__global__ __launch_bounds__(256)
void k_agg(const unsigned short* __restrict__ hwS, const float* __restrict__ inv,
           const int* __restrict__ offs, const int* __restrict__ csrc,
           const float* __restrict__ bias,
           unsigned* __restrict__ aggS, float* __restrict__ stats, int n,
           int ngroups){
  int g   = blockIdx.x & 7;
  int grp = blockIdx.x >> 3;
  int tid = threadIdx.x, lane = tid & 63, wv = tid >> 6;
  int ns = lane >> 2;          // node slot 0..15
  int cp = lane & 3;           // col quad 0..3 (cols g*16 + cp*4 .. +3)
  int nwaves = ngroups * 4;
  int gw = grp * 4 + wv;
  int per = (n + nwaves - 1) / nwaves;
  per = (per + 15) & ~15;      // cohort-aligned chunks
  int n0 = min(gw * per, n), n1 = min(n0 + per, n);

  const u32x2* slice2 = (const u32x2*)((const unsigned*)hwS + (long)g * n * 8);
  u32x2* oslice2 = (u32x2*)(aggS + (long)g * n * 8);

  int cb = g * 16 + cp * 4;
  float b0 = bias[cb], b1 = bias[cb + 1], b2 = bias[cb + 2], b3 = bias[cb + 3];
  float s0 = 0, s1 = 0, s2 = 0, s3 = 0;
  float q0 = 0, q1 = 0, q2 = 0, q3 = 0;

  for (int base = n0; base < n1; base += 16){
    int node = base + ns;
    bool act = node < n1;
    int ndc = act ? node : n1 - 1;
    int e  = offs[ndc];
    int ee = offs[ndc + 1];
    float a0 = 0, a1 = 0, a2 = 0, a3 = 0;

    int i0 = csrc[(e     < ee) ? e     : 0];
    int i1 = csrc[(e + 1 < ee) ? e + 1 : 0];
    int i2 = csrc[(e + 2 < ee) ? e + 2 : 0];
    int i3 = csrc[(e + 3 < ee) ? e + 3 : 0];
    while (__any(e < ee)){
      // prefetch next iteration's indices (independent of this iter's gathers)
      int j0 = csrc[(e + 4 < ee) ? e + 4 : 0];
      int j1 = csrc[(e + 5 < ee) ? e + 5 : 0];
      int j2 = csrc[(e + 6 < ee) ? e + 6 : 0];
      int j3 = csrc[(e + 7 < ee) ? e + 7 : 0];
      u32x2 v0 = slice2[(long)i0 * 4 + cp];
      u32x2 v1 = slice2[(long)i1 * 4 + cp];
      u32x2 v2 = slice2[(long)i2 * 4 + cp];
      u32x2 v3 = slice2[(long)i3 * 4 + cp];
      bool k0 = e < ee, k1 = e + 1 < ee, k2 = e + 2 < ee, k3 = e + 3 < ee;
      v0[0] = k0 ? v0[0] : 0u; v0[1] = k0 ? v0[1] : 0u;
      v1[0] = k1 ? v1[0] : 0u; v1[1] = k1 ? v1[1] : 0u;
      v2[0] = k2 ? v2[0] : 0u; v2[1] = k2 ? v2[1] : 0u;
      v3[0] = k3 ? v3[0] : 0u; v3[1] = k3 ? v3[1] : 0u;
      a0 += (bflo2f(v0[0]) + bflo2f(v1[0])) + (bflo2f(v2[0]) + bflo2f(v3[0]));
      a1 += (bfhi2f(v0[0]) + bfhi2f(v1[0])) + (bfhi2f(v2[0]) + bfhi2f(v3[0]));
      a2 += (bflo2f(v0[1]) + bflo2f(v1[1])) + (bflo2f(v2[1]) + bflo2f(v3[1]));
      a3 += (bfhi2f(v0[1]) + bfhi2f(v1[1])) + (bfhi2f(v2[1]) + bfhi2f(v3[1]));
      i0 = j0; i1 = j1; i2 = j2; i3 = j3;
      e += 4;
    }

    if (act){
      u32x2 sv = slice2[(long)node * 4 + cp];
      float ivd = inv[node];
      a0 = (a0 + bflo2f(sv[0])) * ivd + b0;
      a1 = (a1 + bfhi2f(sv[0])) * ivd + b1;
      a2 = (a2 + bflo2f(sv[1])) * ivd + b2;
      a3 = (a3 + bfhi2f(sv[1])) * ivd + b3;
      u32x2 pk;
      pk[0] = ((unsigned)f2bf(a1) << 16) | (unsigned)f2bf(a0);
      pk[1] = ((unsigned)f2bf(a3) << 16) | (unsigned)f2bf(a2);
      __builtin_nontemporal_store(pk, oslice2 + (long)node * 4 + cp);
      s0 += a0; s1 += a1; s2 += a2; s3 += a3;
      q0 += a0 * a0; q1 += a1 * a1; q2 += a2 * a2; q3 += a3 * a3;
    }
  }

  // fold the 16 node slots (lane bits 2..5) once per kernel
#pragma unroll
  for (int off = 4; off <= 32; off <<= 1){
    s0 += __shfl_xor(s0, off, 64); s1 += __shfl_xor(s1, off, 64);
    s2 += __shfl_xor(s2, off, 64); s3 += __shfl_xor(s3, off, 64);
    q0 += __shfl_xor(q0, off, 64); q1 += __shfl_xor(q1, off, 64);
    q2 += __shfl_xor(q2, off, 64); q3 += __shfl_xor(q3, off, 64);
  }

  __shared__ float red[4][4][8];
  if (ns == 0){
    red[wv][cp][0] = s0; red[wv][cp][1] = s1;
    red[wv][cp][2] = s2; red[wv][cp][3] = s3;
    red[wv][cp][4] = q0; red[wv][cp][5] = q1;
    red[wv][cp][6] = q2; red[wv][cp][7] = q3;
  }
  __syncthreads();
  if (tid < 4){
    float t[8] = {0,0,0,0,0,0,0,0};
#pragma unroll
    for (int w = 0; w < 4; ++w)
#pragma unroll
      for (int j = 0; j < 8; ++j) t[j] += red[w][tid][j];
    int c = g * 16 + tid * 4;
#pragma unroll
    for (int j = 0; j < 4; ++j){
      atomicAdd(&stats[c + j],       t[j]);
      atomicAdd(&stats[128 + c + j], t[4 + j]);
    }
  }
}

// ---------------- pool (fused BN+ReLU of layer 2, sliced bf16 agg) ---------
__global__ __launch_bounds__(256)
void k_pool(const unsigned* __restrict__ aggS, const float* __restrict__ stats,
            const float* __restrict__ gamma, const float* __restrict__ beta,
            float invn, const int* __restrict__ batch,
            float* __restrict__ out, int n){
  __shared__ float psc[128], psh[128];
  int tid = threadIdx.x, lane = tid & 63, wv = tid >> 6;
  if (tid < 128){
    float mean = stats[tid] * invn;
    float var = stats[128 + tid] * invn - mean * mean;
    float isd = rsqrtf(var + 1e-5f);
    float sc = gamma[tid] * isd;
    psc[tid] = sc;
    psh[tid] = beta[tid] - mean * sc;
  }
  __syncthreads();
  int gw = blockIdx.x * 4 + wv;
  int n0 = gw * 64;
  if (n0 >= n) return;
  int n1 = min(n0 + 64, n);
  int c0 = lane * 2;
  int sl = lane >> 3, cp = lane & 7;
  long sbase = (long)sl * n * 8;
  float sc0 = psc[c0], sc1 = psc[c0 + 1];
  float sh0 = psh[c0], sh1 = psh[c0 + 1];
  int g = batch[n0];
  float a0 = 0, a1 = 0;
  for (int nd = n0; nd < n1; ++nd){
    int gn = batch[nd];
    if (gn != g){
      atomicAdd(&out[(long)g * D + c0],     a0);
      atomicAdd(&out[(long)g * D + c0 + 1], a1);
      a0 = 0; a1 = 0; g = gn;
    }
    unsigned v = aggS[sbase + (long)nd * 8 + cp];
    a0 += fmaxf(0.f, bflo2f(v) * sc0 + sh0);
    a1 += fmaxf(0.f, bfhi2f(v) * sc1 + sh1);
  }
  atomicAdd(&out[(long)g * D + c0],     a0);
  atomicAdd(&out[(long)g * D + c0 + 1], a1);
}

extern "C" void kernel_launch(void* const* d_in, const int* in_sizes, int n_in,
                              void* d_out, int out_size, void* d_ws, size_t ws_size,
                              hipStream_t stream){
  const float* x      = (const float*)d_in[0];
  const int*   ei     = (const int*)d_in[1];
  const int*   batch  = (const int*)d_in[2];
  const float* Ws     = (const float*)d_in[3];
  const float* bs     = (const float*)d_in[4];
  const float* gammas = (const float*)d_in[5];
  const float* betas  = (const float*)d_in[6];

  const int E_ = in_sizes[1] / 2;
  const int N_ = in_sizes[2];
  const int* src = ei;
  const int* dst = ei + E_;

  char* p = (char*)d_ws;
  auto alloc = [&](size_t bytes) -> void* {
    void* r = (void*)p;
    p += (bytes + 255) & ~(size_t)255;
    return r;
  };
  unsigned*       bufA   = (unsigned*)      alloc((size_t)N_ * D * 2);   // bf16 agg, sliced
  unsigned short* hwS    = (unsigned short*)alloc((size_t)N_ * D * 2);   // bf16 hw, sliced
  int*            deg    = (int*)           alloc((size_t)N_ * 4);
  float*          inv    = (float*)         alloc((size_t)N_ * 4);
  int*            offs   = (int*)           alloc((size_t)(N_ + 1) * 4);
  int*            rank   = (int*)           alloc((size_t)E_ * 4);
  int*            csrc   = (int*)           alloc((size_t)E_ * 4);
  float*          stats  = (float*)         alloc(3 * 256 * 4);
  int*            csum   = (int*)           alloc(256 * 4);

  hipMemsetAsync(deg,    0, (size_t)N_ * 4, stream);
  hipMemsetAsync(stats,  0, 3 * 256 * 4, stream);
  hipMemsetAsync(d_out,  0, (size_t)out_size * 4, stream);

  float invn = 1.0f / (float)N_;
  int nchunks = (N_ + CHUNK - 1) / CHUNK;
  k_deg       <<<(E_ + 255) / 256, 256, 0, stream>>>(dst, deg, rank, E_);
  k_chunksum  <<<nchunks, 256, 0, stream>>>(deg, csum, N_);
  k_scanchunks<<<1, 256, 0, stream>>>(csum, nchunks);
  k_offsets   <<<nchunks, 256, 0, stream>>>(deg, csum, offs, inv, N_);
  k_csrfill   <<<2048, 256, 0, stream>>>(src, dst, offs, rank, csrc, E_, N_);

  int gemm_blocks = (N_ + 127) / 128;
  int ngroups = 256;                       // R16 balance (R18: 512 hurt)
  for (int l = 0; l < 3; ++l){
    const float* st = (l == 0) ? stats : stats + (size_t)(l - 1) * 256;
    const float* gm = (l == 0) ? gammas : gammas + (size_t)(l - 1) * D;
    const float* bt = (l == 0) ? betas : betas + (size_t)(l - 1) * D;
    k_gemm<<<gemm_blocks, 512, 0, stream>>>(x, (const unsigned short*)bufA,
                                            Ws + (size_t)l * D * D, inv,
                                            st, gm, bt, invn,
                                            (l == 0) ? 0 : 1, hwS, N_);
    k_agg<<<ngroups * 8, 256, 0, stream>>>(hwS, inv, offs, csrc, bs + (size_t)l * D,
                                           bufA, stats + (size_t)l * 256, N_, ngroups);
  }
  k_pool<<<(N_ + 255) / 256, 256, 0, stream>>>(bufA, stats + 2 * 256,
                                               gammas + 2 * D, betas + 2 * D, invn,
                                               batch, (float*)d_out, N_);
}